// Round 2
// baseline (548.204 us; speedup 1.0000x reference)
//
#include <hip/hip_runtime.h>
#include <hip/hip_bf16.h>

typedef _Float16 half8 __attribute__((ext_vector_type(8)));
typedef _Float16 half4 __attribute__((ext_vector_type(4)));
typedef float floatx4 __attribute__((ext_vector_type(4)));

#define EMBED 1024
#define SEQ   2048
#define BATCH 32
#define M_TOT (BATCH * SEQ)   // 65536 rows
#define KDIM  1024
#define NDIM  1024

// ---------------------------------------------------------------------------
// Kernel 1: transpose + convert W[K][N] fp32 -> Wt[N][K] fp16
// ---------------------------------------------------------------------------
__global__ void transpose_w_kernel(const float* __restrict__ W,
                                   _Float16* __restrict__ Wt) {
    __shared__ float t[32][33];
    const int kt = blockIdx.x * 32;
    const int nt = blockIdx.y * 32;
    #pragma unroll
    for (int i = 0; i < 4; ++i)
        t[threadIdx.y + 8 * i][threadIdx.x] =
            W[(size_t)(kt + threadIdx.y + 8 * i) * NDIM + nt + threadIdx.x];
    __syncthreads();
    #pragma unroll
    for (int i = 0; i < 4; ++i)
        Wt[(size_t)(nt + threadIdx.y + 8 * i) * KDIM + kt + threadIdx.x] =
            (_Float16)t[threadIdx.x][threadIdx.y + 8 * i];
}

// ---------------------------------------------------------------------------
// Kernel 2: zero scores + out (atomics accumulate into both)
// ---------------------------------------------------------------------------
__global__ void zero_kernel(float* __restrict__ scores, float* __restrict__ out) {
    const int i = blockIdx.x * 256 + threadIdx.x;
    if (i < M_TOT) scores[i] = 0.0f;
    if (i < BATCH * EMBED) out[i] = 0.0f;
}

// ---------------------------------------------------------------------------
// Kernel 3: fused scores GEMM.  scores[r] += sum_n tanh((x W)[r,n] + b[n]) * ctx[n]
// 128x128 tile, BK=32, 4 waves (each 64x64), mfma_f32_16x16x32_f16.
// A (x) is fp32 in HBM, converted to fp16 while staging to LDS.
// B (Wt) is fp16 [N][K].
// ---------------------------------------------------------------------------
__global__ __launch_bounds__(256) void score_gemm_kernel(
    const float* __restrict__ x, const _Float16* __restrict__ Wt,
    const float* __restrict__ bias, const float* __restrict__ ctx,
    float* __restrict__ scores) {
    // LDS tiles, pitch = 40 halves (80 B) to break bank conflicts
    __shared__ _Float16 As[128 * 40];
    __shared__ _Float16 Bs[128 * 40];

    const int bid = blockIdx.x;
    const int bm = bid >> 3;      // 512 row tiles
    const int bn = bid & 7;       // 8 col tiles (n-fastest for A-panel reuse)
    const int tid = threadIdx.x;
    const int lane = tid & 63;
    const int wid = tid >> 6;
    const int wm = wid >> 1;      // 2x2 wave grid
    const int wn = wid & 1;

    // A staging: 128 rows x 32 k fp32 = 1024 float4; thread t -> (row t>>3 + 32i, chunk t&7)
    const int af  = tid & 7;
    const int ar0 = tid >> 3;
    // B staging: 128 rows x 32 k fp16 = 512 x 16B; thread t -> (row t>>2 + 64i, chunk t&3)
    const int bc  = tid & 3;
    const int bn0 = tid >> 2;

    const float4* xg = (const float4*)x;
    const int4*   wg = (const int4*)Wt;   // 128 int4 per Wt row

    float4 aReg[4];
    int4   bReg[2];

    // prefetch k-tile 0
    {
        const int kt = 0;
        #pragma unroll
        for (int i = 0; i < 4; ++i)
            aReg[i] = xg[(size_t)(bm * 128 + ar0 + 32 * i) * (KDIM / 4) + kt * 8 + af];
        #pragma unroll
        for (int i = 0; i < 2; ++i)
            bReg[i] = wg[(size_t)(bn * 128 + bn0 + 64 * i) * (KDIM / 8) + kt * 4 + bc];
    }

    floatx4 acc[4][4] = {};

    for (int kt = 0; kt < KDIM / 32; ++kt) {
        __syncthreads();
        // store staged regs -> LDS (fp32 -> fp16 for A)
        #pragma unroll
        for (int i = 0; i < 4; ++i) {
            half4 h;
            h[0] = (_Float16)aReg[i].x; h[1] = (_Float16)aReg[i].y;
            h[2] = (_Float16)aReg[i].z; h[3] = (_Float16)aReg[i].w;
            *(half4*)&As[(ar0 + 32 * i) * 40 + af * 4] = h;
        }
        #pragma unroll
        for (int i = 0; i < 2; ++i)
            *(int4*)&Bs[(bn0 + 64 * i) * 40 + bc * 8] = bReg[i];
        __syncthreads();

        // prefetch next k-tile while MFMAs run
        if (kt + 1 < KDIM / 32) {
            #pragma unroll
            for (int i = 0; i < 4; ++i)
                aReg[i] = xg[(size_t)(bm * 128 + ar0 + 32 * i) * (KDIM / 4) + (kt + 1) * 8 + af];
            #pragma unroll
            for (int i = 0; i < 2; ++i)
                bReg[i] = wg[(size_t)(bn * 128 + bn0 + 64 * i) * (KDIM / 8) + (kt + 1) * 4 + bc];
        }

        half8 afr[4], bfr[4];
        #pragma unroll
        for (int m = 0; m < 4; ++m)
            afr[m] = *(const half8*)&As[(wm * 64 + m * 16 + (lane & 15)) * 40 + (lane >> 4) * 8];
        #pragma unroll
        for (int n = 0; n < 4; ++n)
            bfr[n] = *(const half8*)&Bs[(wn * 64 + n * 16 + (lane & 15)) * 40 + (lane >> 4) * 8];

        #pragma unroll
        for (int m = 0; m < 4; ++m)
            #pragma unroll
            for (int n = 0; n < 4; ++n)
                acc[m][n] = __builtin_amdgcn_mfma_f32_16x16x32_f16(afr[m], bfr[n], acc[m][n], 0, 0, 0);
    }

    // Epilogue: tanh + ctx dot + row reduce + atomic accumulate
    float bv[4], cv[4];
    #pragma unroll
    for (int n = 0; n < 4; ++n) {
        const int col = bn * 128 + wn * 64 + n * 16 + (lane & 15);
        bv[n] = bias[col];
        cv[n] = ctx[col];
    }
    #pragma unroll
    for (int m = 0; m < 4; ++m) {
        #pragma unroll
        for (int j = 0; j < 4; ++j) {
            float partial = 0.0f;
            #pragma unroll
            for (int n = 0; n < 4; ++n)
                partial += tanhf(acc[m][n][j] + bv[n]) * cv[n];
            #pragma unroll
            for (int off = 1; off < 16; off <<= 1)
                partial += __shfl_xor(partial, off, 64);
            if ((lane & 15) == 0) {
                const int rowg = bm * 128 + wm * 64 + m * 16 + (lane >> 4) * 4 + j;
                atomicAdd(&scores[rowg], partial);
            }
        }
    }
}

// ---------------------------------------------------------------------------
// Kernel 4: softmax over seq dim per batch. 32 blocks x 256 threads.
// ---------------------------------------------------------------------------
__global__ void softmax_kernel(const float* __restrict__ scores,
                               float* __restrict__ weights) {
    const int bb = blockIdx.x;
    const int tid = threadIdx.x;
    const float* s = scores + (size_t)bb * SEQ;
    float* w = weights + (size_t)bb * SEQ;

    __shared__ float red[8];

    float v[8];
    float mx = -1e30f;
    #pragma unroll
    for (int i = 0; i < 8; ++i) {
        v[i] = s[tid + i * 256];
        mx = fmaxf(mx, v[i]);
    }
    #pragma unroll
    for (int off = 1; off < 64; off <<= 1)
        mx = fmaxf(mx, __shfl_xor(mx, off, 64));
    const int wv = tid >> 6;
    if ((tid & 63) == 0) red[wv] = mx;
    __syncthreads();
    mx = fmaxf(fmaxf(red[0], red[1]), fmaxf(red[2], red[3]));

    float sum = 0.0f;
    #pragma unroll
    for (int i = 0; i < 8; ++i) {
        v[i] = __expf(v[i] - mx);
        sum += v[i];
    }
    #pragma unroll
    for (int off = 1; off < 64; off <<= 1)
        sum += __shfl_xor(sum, off, 64);
    if ((tid & 63) == 0) red[4 + wv] = sum;
    __syncthreads();
    sum = red[4] + red[5] + red[6] + red[7];
    const float inv = 1.0f / sum;
    #pragma unroll
    for (int i = 0; i < 8; ++i)
        w[tid + i * 256] = v[i] * inv;
}

// ---------------------------------------------------------------------------
// Kernel 5: weighted pooling. out[b,e] = sum_s w[b,s] * x[b,s,e]
// grid = 32 batches x 16 seq-chunks (128 rows each); 256 threads, float4/thread.
// ---------------------------------------------------------------------------
__global__ __launch_bounds__(256) void pool_kernel(const float* __restrict__ x,
                                                   const float* __restrict__ weights,
                                                   float* __restrict__ out) {
    const int bb = blockIdx.x >> 4;
    const int sc = blockIdx.x & 15;
    const int tid = threadIdx.x;

    const float4* xb = (const float4*)(x + (size_t)bb * SEQ * EMBED) +
                       (size_t)(sc * 128) * (EMBED / 4) + tid;
    const float* wb = weights + (size_t)bb * SEQ + sc * 128;

    float ax = 0.f, ay = 0.f, az = 0.f, aw = 0.f;
    #pragma unroll 4
    for (int s = 0; s < 128; ++s) {
        const float wgt = wb[s];
        const float4 xv = xb[(size_t)s * (EMBED / 4)];
        ax += wgt * xv.x; ay += wgt * xv.y; az += wgt * xv.z; aw += wgt * xv.w;
    }
    float* o = out + (size_t)bb * EMBED + tid * 4;
    atomicAdd(o + 0, ax);
    atomicAdd(o + 1, ay);
    atomicAdd(o + 2, az);
    atomicAdd(o + 3, aw);
}

// ---------------------------------------------------------------------------
extern "C" void kernel_launch(void* const* d_in, const int* in_sizes, int n_in,
                              void* d_out, int out_size, void* d_ws, size_t ws_size,
                              hipStream_t stream) {
    const float* x   = (const float*)d_in[0];
    const float* W   = (const float*)d_in[1];
    const float* b   = (const float*)d_in[2];
    const float* ctx = (const float*)d_in[3];
    float* out = (float*)d_out;

    char* ws = (char*)d_ws;
    _Float16* Wt    = (_Float16*)ws;                          // 2 MB
    float*    scores  = (float*)(ws + (2u << 20));            // 256 KB
    float*    weights = (float*)(ws + (2u << 20) + (256u << 10)); // 256 KB

    hipLaunchKernelGGL(transpose_w_kernel, dim3(32, 32), dim3(32, 8), 0, stream, W, Wt);
    hipLaunchKernelGGL(zero_kernel, dim3(M_TOT / 256), dim3(256), 0, stream, scores, out);
    hipLaunchKernelGGL(score_gemm_kernel, dim3(4096), dim3(256), 0, stream,
                       x, Wt, b, ctx, scores);
    hipLaunchKernelGGL(softmax_kernel, dim3(BATCH), dim3(256), 0, stream, scores, weights);
    hipLaunchKernelGGL(pool_kernel, dim3(BATCH * 16), dim3(256), 0, stream,
                       x, weights, out);
}